// Round 8
// baseline (2891.440 us; speedup 1.0000x reference)
//
#include <hip/hip_runtime.h>
#include <cstdint>
#include <cstddef>

// Problem constants
#define BB 4
#define SS 4096
#define HH 1024
#define PP 10
#define LL 4106              // P + S
#define NTILES 129
#define CHUNKS_PB (NTILES * 4096)   // 16B-chunks per batch plane (= 528384)
#define TILE_CHUNKS 4096            // chunks per tile
#define LOG2E 1.44269504088896f

typedef __attribute__((ext_vector_type(8))) _Float16 half8v;   // 4 VGPR MFMA frag
typedef __attribute__((ext_vector_type(16))) float float16v;   // 32x32 acc
typedef __attribute__((ext_vector_type(4))) float float4v;

union hu16 { _Float16 h; unsigned short u; };

__device__ __forceinline__ half8v cvt8h(float4v f0, float4v f1) {
  half8v h;
  h[0] = (_Float16)f0[0]; h[1] = (_Float16)f0[1];
  h[2] = (_Float16)f0[2]; h[3] = (_Float16)f0[3];
  h[4] = (_Float16)f1[0]; h[5] = (_Float16)f1[1];
  h[6] = (_Float16)f1[2]; h[7] = (_Float16)f1[3];
  return h;
}
__device__ __forceinline__ unsigned pack2h(float a, float b) {
  hu16 x, y; x.h = (_Float16)a; y.h = (_Float16)b;
  return (unsigned)x.u | ((unsigned)y.u << 16);
}

// DPP row-16 reductions (VALU pipe)
template<int C>
__device__ __forceinline__ float dppf(float x) {
  return __int_as_float(
      __builtin_amdgcn_update_dpp(0, __float_as_int(x), C, 0xF, 0xF, true));
}
__device__ __forceinline__ float row16_max(float x) {
  x = fmaxf(x, dppf<0xB1>(x));
  x = fmaxf(x, dppf<0x4E>(x));
  x = fmaxf(x, dppf<0x140>(x));
  x = fmaxf(x, dppf<0x141>(x));
  return x;
}
__device__ __forceinline__ float row16_sum(float x) {
  x += dppf<0xB1>(x);
  x += dppf<0x4E>(x);
  x += dppf<0x140>(x);
  x += dppf<0x141>(x);
  return x;
}

#define LGKM_BAR() do { \
  asm volatile("s_waitcnt lgkmcnt(0)" ::: "memory"); \
  __builtin_amdgcn_s_barrier(); \
  asm volatile("" ::: "memory"); } while (0)

// ---------- pre-kernels: fp16 planes in 32x32x16 MFMA-fragment order ----------
// K chunk id = ((it*64 + ktg)*2 + hi)*32 + col : holds K[n=it*32+col][d=ktg*16+hi*8 ..+8)
__global__ __launch_bounds__(256) void conv_k(const float* __restrict__ prefix_k,
                                              const float* __restrict__ key,
                                              _Float16* __restrict__ kp) {
  const int b = blockIdx.y;
  const int id = blockIdx.x * 256 + threadIdx.x;       // < CHUNKS_PB
  const int col = id & 31, hi = (id >> 5) & 1, ktg = (id >> 6) & 63, it = id >> 12;
  const int n = it * 32 + col;
  const int d = ktg * 16 + hi * 8;
  float4v f0 = {0.f, 0.f, 0.f, 0.f}, f1 = {0.f, 0.f, 0.f, 0.f};
  if (n < LL) {
    const float* src = (n < PP) ? prefix_k + (size_t)n * HH + d
                                : key + ((size_t)b * SS + (n - PP)) * HH + d;
    f0 = *(const float4v*)src; f1 = *(const float4v*)(src + 4);
  }
  *(half8v*)(kp + ((size_t)b * CHUNKS_PB + id) * 8) = cvt8h(f0, f1);
}

// V chunk id = (((it*2+kt)*32 + dtg)*2 + hi)*32 + dcol :
//   holds V[n=it*32+kt*16+hi*8+j][d=dtg*32+dcol], j=0..7
__global__ __launch_bounds__(256) void conv_v(const float* __restrict__ prefix_v,
                                              const float* __restrict__ value,
                                              _Float16* __restrict__ vp) {
  const int b = blockIdx.y;
  const int id = blockIdx.x * 256 + threadIdx.x;
  const int dcol = id & 31, hi = (id >> 5) & 1, dtg = (id >> 6) & 31,
            kt = (id >> 11) & 1, it = id >> 12;
  const int d = dtg * 32 + dcol;
  const int nb = it * 32 + kt * 16 + hi * 8;
  half8v h;
  #pragma unroll
  for (int j = 0; j < 8; ++j) {
    int n = nb + j;
    float f = 0.f;
    if (n < LL)
      f = (n < PP) ? prefix_v[(size_t)n * HH + d]
                   : value[((size_t)b * SS + (n - PP)) * HH + d];
    h[j] = (_Float16)f;
  }
  *(half8v*)(vp + ((size_t)b * CHUNKS_PB + id) * 8) = h;
}

// ---------------- fused flash attention, v8: 32x32x16 + ds_add reduce ----------------
// 8 waves; wave w owns D-slice [128w,128w+128), M=32 rows, KV tile 32.
// QK partials accumulate across waves via ds_add_f32 into a shared zeroed tile;
// softmax reads the summed row (1 b64) and re-zeroes it.
template<int PATH>
__global__ __launch_bounds__(512, 2) void attn_fused(
    const float* __restrict__ q,
    const float* __restrict__ key,
    const float* __restrict__ value,
    const float* __restrict__ prefix_k,
    const float* __restrict__ prefix_v,
    const _Float16* __restrict__ kp,
    const _Float16* __restrict__ vp,
    float* __restrict__ out)
{
  __shared__ __align__(16) float sbuf0[32][36];           // summed S, bank 0 (even tiles)
  __shared__ __align__(16) float sbuf1[32][36];           // bank 1 (odd tiles)
  __shared__ __align__(16) unsigned short Pl0[32][40];
  __shared__ __align__(16) unsigned short Pl1[32][40];
  __shared__ __align__(16) float sc0[32], sc1[32];
  __shared__ __align__(16) float l_l[32];

  const int tid = threadIdx.x;
  const int w = tid >> 6, ln = tid & 63;
  const int col32 = ln & 31;          // lane's 32-col index (KV-n for S, d for O)
  const int hi = ln >> 5;             // half-wave
  const int bid = blockIdx.x, xcd = bid & 7, b = xcd >> 1;
  const int qt = ((bid >> 3) << 1) | (xcd & 1);
  const int q0 = qt * 32;
  const int dbase = w * 128;

  // zero both S banks once
  {
    float* z0 = &sbuf0[0][0];
    float* z1 = &sbuf1[0][0];
    for (int z = tid; z < 32 * 36; z += 512) { z0[z] = 0.f; z1[z] = 0.f; }
  }

  // Q fragments fp16 (32x32x16 A-layout: row=ln&31, k=hi*8+j within 16-chunk)
  half8v qf[8];
  #pragma unroll
  for (int kt = 0; kt < 8; ++kt) {
    const float* p = q + ((size_t)(b * SS + q0 + col32)) * HH + dbase + kt * 16 + hi * 8;
    qf[kt] = cvt8h(*(const float4v*)p, *(const float4v*)(p + 4));
  }

  float16v o4[4];
  #pragma unroll
  for (int ct = 0; ct < 4; ++ct)
    #pragma unroll
    for (int r = 0; r < 16; ++r) o4[ct][r] = 0.f;
  float m_r = -1e30f, l_r = 0.f;
  float16v sacc;                       // QK acc, alive between qk-mfma and qk-add

  const _Float16* kbase = kp + ((size_t)b * CHUNKS_PB + (size_t)(w * 8) * 64 + hi * 32 + col32) * 8;
  const _Float16* vbase = vp + ((size_t)b * CHUNKS_PB + (size_t)w * 256 + hi * 32 + col32) * 8;

  half8v kreg[8];        // K(i) frags (kt)
  half8v vreg[2][4];     // V(i-2) frags [kt][ct]
  if constexpr (PATH == 0) {
    #pragma unroll
    for (int kt = 0; kt < 8; ++kt)
      kreg[kt] = *(const half8v*)(kbase + (size_t)(kt * 64) * 8);
  }

  const int srow = w * 4 + (ln >> 4);
  const int c0 = (ln & 15) * 2;

  // ---- phase helpers ----
  auto qk_mfma = [&](int i) __attribute__((always_inline)) {
    #pragma unroll
    for (int r = 0; r < 16; ++r) sacc[r] = 0.f;
    #pragma unroll
    for (int kt = 0; kt < 8; ++kt) {
      half8v kb;
      if constexpr (PATH == 0) {
        kb = kreg[kt];
      } else {
        int n = i * 32 + col32;
        int nc = (n < LL) ? n : 0;
        const float* kpp = (nc < PP) ? (prefix_k + (size_t)nc * HH)
                                     : (key + ((size_t)b * SS + (nc - PP)) * HH);
        kpp += dbase + kt * 16 + hi * 8;
        kb = cvt8h(*(const float4v*)kpp, *(const float4v*)(kpp + 4));
      }
      sacc = __builtin_amdgcn_mfma_f32_32x32x16_f16(qf[kt], kb, sacc, 0, 0, 0);
    }
    if constexpr (PATH == 0) {   // prefetch K(i+1); benign 1-tile overrun into vp
      kbase += (size_t)TILE_CHUNKS * 8;
      #pragma unroll
      for (int kt = 0; kt < 8; ++kt)
        kreg[kt] = *(const half8v*)(kbase + (size_t)(kt * 64) * 8);
    }
  };

  auto qk_add = [&](float (*sb)[36]) __attribute__((always_inline)) {
    // C-layout: reg r -> row (r&3)+8*(r>>2)+4*hi, col = col32
    #pragma unroll
    for (int r = 0; r < 16; ++r) {
      const int row = (r & 3) + 8 * (r >> 2) + 4 * hi;
      atomicAdd(&sb[row][col32], sacc[r]);
    }
  };

  auto do_softmax = [&](int t, float (*sb)[36],
                        unsigned short (*plw)[40], float* scw)
      __attribute__((always_inline)) {
    float2 tv = *(const float2*)&sb[srow][c0];          // summed S
    *(float2*)&sb[srow][c0] = make_float2(0.f, 0.f);    // re-zero for tile t+2
    float s0 = tv.x, s1 = tv.y;
    if constexpr (PATH == 1) {
      if (t * 32 + c0 >= LL)     s0 = -1e30f;
      if (t * 32 + c0 + 1 >= LL) s1 = -1e30f;
    }
    const float mx = row16_max(fmaxf(s0, s1));
    const float m_new = fmaxf(m_r, mx);
    const float scp = exp2f((m_r - m_new) * LOG2E);
    const float p0 = exp2f((s0 - m_new) * LOG2E);
    const float p1 = exp2f((s1 - m_new) * LOG2E);
    const float ts = row16_sum(p0 + p1);
    l_r = l_r * scp + ts;
    m_r = m_new;
    *(unsigned*)&plw[srow][c0] = pack2h(p0, p1);
    if ((ln & 15) == 0) scw[srow] = scp;
  };

  auto do_pv = [&](int t, const unsigned short (*plr)[40], const float* scr)
      __attribute__((always_inline)) {
    float4v scv[4];
    #pragma unroll
    for (int g4 = 0; g4 < 4; ++g4)
      scv[g4] = *(const float4v*)&scr[g4 * 8 + 4 * hi];
    #pragma unroll
    for (int ct = 0; ct < 4; ++ct)
      #pragma unroll
      for (int r = 0; r < 16; ++r)
        o4[ct][r] *= scv[r >> 2][r & 3];
    half8v pa[2];
    #pragma unroll
    for (int kt = 0; kt < 2; ++kt)
      pa[kt] = *(const half8v*)&plr[col32][kt * 16 + hi * 8];
    #pragma unroll
    for (int ct = 0; ct < 4; ++ct)
      #pragma unroll
      for (int kt = 0; kt < 2; ++kt) {
        half8v vb;
        if constexpr (PATH == 0) {
          vb = vreg[kt][ct];
        } else {
          const int d = dbase + ct * 32 + col32;
          #pragma unroll
          for (int j = 0; j < 8; ++j) {
            int n = t * 32 + kt * 16 + hi * 8 + j;
            int nc = (n < LL) ? n : 0;       // clamped rows have P==0
            float f = (nc < PP) ? prefix_v[(size_t)nc * HH + d]
                                : value[((size_t)b * SS + (nc - PP)) * HH + d];
            vb[j] = (_Float16)f;
          }
        }
        o4[ct] = __builtin_amdgcn_mfma_f32_32x32x16_f16(pa[kt], vb, o4[ct], 0, 0, 0);
      }
  };

  auto load_v = [&]() __attribute__((always_inline)) {
    if constexpr (PATH == 0) {
      #pragma unroll
      for (int kt = 0; kt < 2; ++kt)
        #pragma unroll
        for (int ct = 0; ct < 4; ++ct)
          vreg[kt][ct] = *(const half8v*)(vbase + (size_t)(kt * 2048 + ct * 64) * 8);
      vbase += (size_t)TILE_CHUNKS * 8;
    }
  };

  // ---- pipeline ----
  LGKM_BAR();   // zero-init visible
  qk_mfma(0); qk_add(sbuf0);
  LGKM_BAR();
  qk_mfma(1); do_softmax(0, sbuf0, Pl0, sc0); qk_add(sbuf1); load_v();
  LGKM_BAR();
  int i = 2;
  for (; i + 1 < NTILES; i += 2) {
    qk_mfma(i);
    do_pv(i - 2, Pl0, sc0);
    do_softmax(i - 1, sbuf1, Pl1, sc1);
    qk_add(sbuf0);
    load_v();
    LGKM_BAR();
    qk_mfma(i + 1);
    do_pv(i - 1, Pl1, sc1);
    do_softmax(i, sbuf0, Pl0, sc0);
    qk_add(sbuf1);
    load_v();
    LGKM_BAR();
  }
  // tail steady iter i = NTILES-1 = 128 (even bank)
  qk_mfma(NTILES - 1);
  do_pv(NTILES - 3, Pl0, sc0);
  do_softmax(NTILES - 2, sbuf1, Pl1, sc1);
  qk_add(sbuf0);
  load_v();
  LGKM_BAR();
  do_pv(NTILES - 2, Pl1, sc1);
  do_softmax(NTILES - 1, sbuf0, Pl0, sc0);
  load_v();
  LGKM_BAR();
  do_pv(NTILES - 1, Pl0, sc0);

  // ---- finalize ----
  if ((ln & 15) == 0) l_l[srow] = l_r;
  LGKM_BAR();
  float4v llv[4];
  #pragma unroll
  for (int g4 = 0; g4 < 4; ++g4)
    llv[g4] = *(const float4v*)&l_l[g4 * 8 + 4 * hi];
  #pragma unroll
  for (int ct = 0; ct < 4; ++ct)
    #pragma unroll
    for (int r = 0; r < 16; ++r) {
      const int row = (r & 3) + 8 * (r >> 2) + 4 * hi;
      out[((size_t)(b * SS + q0 + row)) * HH + dbase + ct * 32 + col32]
          = o4[ct][r] / llv[r >> 2][r & 3];
    }
}

extern "C" void kernel_launch(void* const* d_in, const int* in_sizes, int n_in,
                              void* d_out, int out_size, void* d_ws, size_t ws_size,
                              hipStream_t stream) {
  const float* q        = (const float*)d_in[0];
  const float* key      = (const float*)d_in[1];
  const float* value    = (const float*)d_in[2];
  const float* prefix_k = (const float*)d_in[3];
  const float* prefix_v = (const float*)d_in[4];
  float* out = (float*)d_out;

  const size_t PLANE = (size_t)BB * CHUNKS_PB * 8;              // fp16 elems per plane
  const size_t NEED  = 2 * PLANE * sizeof(unsigned short);      // 67.6 MB

  if (ws_size >= NEED) {
    _Float16* kp = (_Float16*)d_ws;
    _Float16* vp = kp + PLANE;
    conv_k<<<dim3(CHUNKS_PB / 256, BB), 256, 0, stream>>>(prefix_k, key, kp);
    conv_v<<<dim3(CHUNKS_PB / 256, BB), 256, 0, stream>>>(prefix_v, value, vp);
    attn_fused<0><<<512, 512, 0, stream>>>(q, key, value, prefix_k, prefix_v, kp, vp, out);
  } else {
    attn_fused<1><<<512, 512, 0, stream>>>(q, key, value, prefix_k, prefix_v,
                                           nullptr, nullptr, out);
  }
}

// Round 9
// 1183.028 us; speedup vs baseline: 2.4441x; 2.4441x over previous
//
#include <hip/hip_runtime.h>
#include <cstdint>
#include <cstddef>

// Problem constants
#define BB 4
#define SS 4096
#define HH 1024
#define PP 10
#define LL 4106              // P + S
#define NTILES 129
#define CHUNKS_PB (NTILES * 4096)   // 16B-chunks per batch plane (= 528384)
#define TILE_ELEMS (4096 * 8)       // fp16 elems per tile in a plane
#define LOG2E 1.44269504088896f

typedef __attribute__((ext_vector_type(8))) _Float16 half8v;  // 4 VGPR MFMA frag
typedef __attribute__((ext_vector_type(4))) float float4v;

union hu16 { _Float16 h; unsigned short u; };

__device__ __forceinline__ half8v cvt8h(float4v f0, float4v f1) {
  half8v h;
  h[0] = (_Float16)f0[0]; h[1] = (_Float16)f0[1];
  h[2] = (_Float16)f0[2]; h[3] = (_Float16)f0[3];
  h[4] = (_Float16)f1[0]; h[5] = (_Float16)f1[1];
  h[6] = (_Float16)f1[2]; h[7] = (_Float16)f1[3];
  return h;
}
__device__ __forceinline__ unsigned pack2h(float a, float b) {
  hu16 x, y; x.h = (_Float16)a; y.h = (_Float16)b;
  return (unsigned)x.u | ((unsigned)y.u << 16);
}

// DPP row-16 reductions (VALU pipe)
template<int C>
__device__ __forceinline__ float dppf(float x) {
  return __int_as_float(
      __builtin_amdgcn_update_dpp(0, __float_as_int(x), C, 0xF, 0xF, true));
}
__device__ __forceinline__ float row16_max(float x) {
  x = fmaxf(x, dppf<0xB1>(x));
  x = fmaxf(x, dppf<0x4E>(x));
  x = fmaxf(x, dppf<0x140>(x));
  x = fmaxf(x, dppf<0x141>(x));
  return x;
}
__device__ __forceinline__ float row16_sum(float x) {
  x += dppf<0xB1>(x);
  x += dppf<0x4E>(x);
  x += dppf<0x140>(x);
  x += dppf<0x141>(x);
  return x;
}

#define LGKM_BAR() do { \
  asm volatile("s_waitcnt lgkmcnt(0)" ::: "memory"); \
  __builtin_amdgcn_s_barrier(); \
  asm volatile("" ::: "memory"); } while (0)

// ---------- pre-kernels: fp16 planes in MFMA-fragment order (unchanged) ----------
__global__ __launch_bounds__(256) void conv_k(const float* __restrict__ prefix_k,
                                              const float* __restrict__ key,
                                              _Float16* __restrict__ kp) {
  const int b = blockIdx.y;
  const int id = blockIdx.x * 256 + threadIdx.x;       // < CHUNKS_PB
  const int li = id & 15, g = (id >> 4) & 3, ktp = (id >> 6) & 31,
            nt = (id >> 11) & 1, it = id >> 12;
  const int n = it * 32 + nt * 16 + li;
  const int d = ktp * 32 + g * 8;
  float4v f0 = {0.f, 0.f, 0.f, 0.f}, f1 = {0.f, 0.f, 0.f, 0.f};
  if (n < LL) {
    const float* src = (n < PP) ? prefix_k + (size_t)n * HH + d
                                : key + ((size_t)b * SS + (n - PP)) * HH + d;
    f0 = *(const float4v*)src; f1 = *(const float4v*)(src + 4);
  }
  *(half8v*)(kp + ((size_t)b * CHUNKS_PB + id) * 8) = cvt8h(f0, f1);
}

__global__ __launch_bounds__(256) void conv_v(const float* __restrict__ prefix_v,
                                              const float* __restrict__ value,
                                              _Float16* __restrict__ vp) {
  const int b = blockIdx.y;
  const int id = blockIdx.x * 256 + threadIdx.x;
  const int d = id & 1023, g = (id >> 10) & 3, it = id >> 12;
  const int nb = it * 32 + g * 8;
  half8v h;
  #pragma unroll
  for (int j = 0; j < 8; ++j) {
    int n = nb + j;
    float f = 0.f;
    if (n < LL)
      f = (n < PP) ? prefix_v[(size_t)n * HH + d]
                   : value[((size_t)b * SS + (n - PP)) * HH + d];
    h[j] = (_Float16)f;
  }
  *(half8v*)(vp + ((size_t)b * CHUNKS_PB + id) * 8) = h;
}

// ---------------- fused flash attention, v9: twin 32-row tiles (Mq=64) ----------------
// 256 blocks (1/CU), 8 waves, wave w owns D-slice [128w,128w+128) for BOTH tiles.
// K/V fragments loaded once per iter, shared by tiles A (rows q0..q0+31) and
// B (q0+32..q0+63) -> L2 traffic halves vs Mq=32. v7's 1-barrier 3-deep pipeline.
template<int PATH>
__global__ __launch_bounds__(512, 2) void attn_fused(
    const float* __restrict__ q,
    const float* __restrict__ key,
    const float* __restrict__ value,
    const float* __restrict__ prefix_k,
    const float* __restrict__ prefix_v,
    const _Float16* __restrict__ kp,
    const _Float16* __restrict__ vp,
    float* __restrict__ out)
{
  __shared__ __align__(16) float sbA0[8][32][33], sbA1[8][32][33];   // 33.8 KB each
  __shared__ __align__(16) float sbB0[8][32][33], sbB1[8][32][33];
  __shared__ __align__(16) unsigned short PlA0[32][40], PlA1[32][40];
  __shared__ __align__(16) unsigned short PlB0[32][40], PlB1[32][40];
  __shared__ float scA0[32], scA1[32], scB0[32], scB1[32];
  __shared__ float lA[32], lB[32];

  const int tid = threadIdx.x;
  const int w = tid >> 6, ln = tid & 63, g = ln >> 4, li = ln & 15;
  const int bid = blockIdx.x, xcd = bid & 7, b = xcd >> 1;
  const int qt = ((bid >> 3) << 1) | (xcd & 1);   // 0..63
  const int q0 = qt * 64;
  const int dbase = w * 128;

  // Q fragments fp16 for both tiles: A-layout row=li, k=g*8+j
  half8v qfA[2][4], qfB[2][4];
  #pragma unroll
  for (int mt = 0; mt < 2; ++mt)
    #pragma unroll
    for (int kt = 0; kt < 4; ++kt) {
      const float* pA = q + ((size_t)(b * SS + q0 + mt * 16 + li)) * HH + dbase + kt * 32 + g * 8;
      const float* pB = pA + (size_t)32 * HH;
      qfA[mt][kt] = cvt8h(*(const float4v*)pA, *(const float4v*)(pA + 4));
      qfB[mt][kt] = cvt8h(*(const float4v*)pB, *(const float4v*)(pB + 4));
    }

  float4v z4 = {0.f, 0.f, 0.f, 0.f};
  float4v oA[2][8], oB[2][8];
  #pragma unroll
  for (int mt = 0; mt < 2; ++mt)
    #pragma unroll
    for (int dt = 0; dt < 8; ++dt) { oA[mt][dt] = z4; oB[mt][dt] = z4; }
  float m_rA = -1e30f, l_rA = 0.f, m_rB = -1e30f, l_rB = 0.f;

  const _Float16* kbase = kp + ((size_t)b * CHUNKS_PB + (size_t)(w * 4) * 64 + g * 16 + li) * 8;
  const _Float16* vbase = vp + ((size_t)b * CHUNKS_PB + (size_t)g * 1024 + dbase + li) * 8;

  half8v kreg[8];   // K(i) frags, shared by A and B
  half8v vreg[8];   // V(i-2) frags, shared by A and B

  const int srow = w * 4 + (ln >> 4);     // slab row this lane handles in softmax
  const int c0 = (ln & 15) * 2;

  auto kload = [&]() __attribute__((always_inline)) {
    if constexpr (PATH == 0) {
      #pragma unroll
      for (int kt = 0; kt < 4; ++kt)
        #pragma unroll
        for (int nt = 0; nt < 2; ++nt)
          kreg[kt * 2 + nt] = *(const half8v*)(kbase + (size_t)(nt * 2048 + kt * 64) * 8);
      kbase += TILE_ELEMS;   // benign overrun past the plane after the last tile
    }
  };

  auto vload = [&]() __attribute__((always_inline)) {
    if constexpr (PATH == 0) {
      #pragma unroll
      for (int dt = 0; dt < 8; ++dt)
        vreg[dt] = *(const half8v*)(vbase + (size_t)(dt * 16) * 8);
      vbase += TILE_ELEMS;
    }
  };

  // QK for one tile into one named sbuf bank
  auto do_qk = [&](int i, const half8v (&qf)[2][4], float (*sb)[32][33])
      __attribute__((always_inline)) {
    float4v sacc[2][2];
    sacc[0][0] = z4; sacc[0][1] = z4; sacc[1][0] = z4; sacc[1][1] = z4;
    #pragma unroll
    for (int kt = 0; kt < 4; ++kt) {
      half8v kb[2];
      if constexpr (PATH == 0) {
        kb[0] = kreg[kt * 2 + 0]; kb[1] = kreg[kt * 2 + 1];
      } else {
        #pragma unroll
        for (int nt = 0; nt < 2; ++nt) {
          int n = i * 32 + nt * 16 + li;
          int nc = (n < LL) ? n : 0;
          const float* kpp = (nc < PP) ? (prefix_k + (size_t)nc * HH)
                                       : (key + ((size_t)b * SS + (nc - PP)) * HH);
          kpp += dbase + kt * 32 + g * 8;
          kb[nt] = cvt8h(*(const float4v*)kpp, *(const float4v*)(kpp + 4));
        }
      }
      #pragma unroll
      for (int mt = 0; mt < 2; ++mt)
        #pragma unroll
        for (int nt = 0; nt < 2; ++nt)
          sacc[mt][nt] = __builtin_amdgcn_mfma_f32_16x16x32_f16(qf[mt][kt], kb[nt], sacc[mt][nt], 0, 0, 0);
    }
    // C/D: row = g*4+r, col = li
    #pragma unroll
    for (int mt = 0; mt < 2; ++mt)
      #pragma unroll
      for (int nt = 0; nt < 2; ++nt)
        #pragma unroll
        for (int r = 0; r < 4; ++r)
          sb[w][mt * 16 + g * 4 + r][nt * 16 + li] = sacc[mt][nt][r];
  };

  auto do_sm = [&](int t, const float (*sb)[32][33],
                   unsigned short (*plw)[40], float* scw, float& m_r, float& l_r)
      __attribute__((always_inline)) {
    float s0 = 0.f, s1 = 0.f;
    #pragma unroll
    for (int bw = 0; bw < 8; ++bw) {
      float2 tv = *(const float2*)&sb[bw][srow][c0];
      s0 += tv.x; s1 += tv.y;
    }
    if constexpr (PATH == 1) {
      if (t * 32 + c0 >= LL)     s0 = -1e30f;
      if (t * 32 + c0 + 1 >= LL) s1 = -1e30f;
    }
    const float mx = row16_max(fmaxf(s0, s1));
    const float m_new = fmaxf(m_r, mx);
    const float scp = exp2f((m_r - m_new) * LOG2E);
    const float p0 = exp2f((s0 - m_new) * LOG2E);
    const float p1 = exp2f((s1 - m_new) * LOG2E);
    const float ts = row16_sum(p0 + p1);
    l_r = l_r * scp + ts;
    m_r = m_new;
    *(unsigned*)&plw[srow][c0] = pack2h(p0, p1);
    if ((ln & 15) == 0) scw[srow] = scp;
  };

  auto do_pv = [&](int t, const unsigned short (*plr)[40], const float* scr,
                   float4v (&o)[2][8]) __attribute__((always_inline)) {
    float scc[2][4];
    #pragma unroll
    for (int mt = 0; mt < 2; ++mt)
      #pragma unroll
      for (int r = 0; r < 4; ++r)
        scc[mt][r] = scr[mt * 16 + g * 4 + r];
    #pragma unroll
    for (int mt = 0; mt < 2; ++mt)
      #pragma unroll
      for (int dt = 0; dt < 8; ++dt)
        #pragma unroll
        for (int r = 0; r < 4; ++r)
          o[mt][dt][r] *= scc[mt][r];
    half8v pa0 = *(const half8v*)&plr[li][g * 8];
    half8v pa1 = *(const half8v*)&plr[16 + li][g * 8];
    #pragma unroll
    for (int dt = 0; dt < 8; ++dt) {
      half8v vb;
      if constexpr (PATH == 0) {
        vb = vreg[dt];
      } else {
        const int d = dbase + dt * 16 + li;
        #pragma unroll
        for (int j = 0; j < 8; ++j) {
          int n = t * 32 + g * 8 + j;
          int nc = (n < LL) ? n : 0;    // clamped rows have P==0
          float f = (nc < PP) ? prefix_v[(size_t)nc * HH + d]
                              : value[((size_t)b * SS + (nc - PP)) * HH + d];
          vb[j] = (_Float16)f;
        }
      }
      o[0][dt] = __builtin_amdgcn_mfma_f32_16x16x32_f16(pa0, vb, o[0][dt], 0, 0, 0);
      o[1][dt] = __builtin_amdgcn_mfma_f32_16x16x32_f16(pa1, vb, o[1][dt], 0, 0, 0);
    }
  };

  // ---- pipeline: prologue / steady (x2 unrolled) / epilogue ----
  // parity: qk(i)->sb*(i&1); sm(t): sb*(t&1) -> Pl*(t&1)/sc*(t&1);
  //         pv(t): Pl*(t&1)/sc*(t&1), vreg = V(t).
  kload();                                   // K(0)
  do_qk(0, qfA, sbA0); do_qk(0, qfB, sbB0); kload();
  LGKM_BAR();
  do_qk(1, qfA, sbA1); do_qk(1, qfB, sbB1); kload();
  do_sm(0, sbA0, PlA0, scA0, m_rA, l_rA);
  do_sm(0, sbB0, PlB0, scB0, m_rB, l_rB);
  vload();                                   // V(0)
  LGKM_BAR();
  int i = 2;
  for (; i + 1 < NTILES; i += 2) {
    // even iter i
    do_qk(i, qfA, sbA0); do_qk(i, qfB, sbB0); kload();
    do_pv(i - 2, PlA0, scA0, oA); do_pv(i - 2, PlB0, scB0, oB);
    do_sm(i - 1, sbA1, PlA1, scA1, m_rA, l_rA);
    do_sm(i - 1, sbB1, PlB1, scB1, m_rB, l_rB);
    vload();                                 // V(i-1)
    LGKM_BAR();
    // odd iter i+1
    do_qk(i + 1, qfA, sbA1); do_qk(i + 1, qfB, sbB1); kload();
    do_pv(i - 1, PlA1, scA1, oA); do_pv(i - 1, PlB1, scB1, oB);
    do_sm(i, sbA0, PlA0, scA0, m_rA, l_rA);
    do_sm(i, sbB0, PlB0, scB0, m_rB, l_rB);
    vload();                                 // V(i)
    LGKM_BAR();
  }
  // tail steady iter i = NTILES-1 = 128 (even bank)
  do_qk(NTILES - 1, qfA, sbA0); do_qk(NTILES - 1, qfB, sbB0);
  do_pv(NTILES - 3, PlA0, scA0, oA); do_pv(NTILES - 3, PlB0, scB0, oB);
  do_sm(NTILES - 2, sbA1, PlA1, scA1, m_rA, l_rA);
  do_sm(NTILES - 2, sbB1, PlB1, scB1, m_rB, l_rB);
  vload();                                   // V(127)
  LGKM_BAR();
  // epilogue
  do_pv(NTILES - 2, PlA1, scA1, oA); do_pv(NTILES - 2, PlB1, scB1, oB);
  do_sm(NTILES - 1, sbA0, PlA0, scA0, m_rA, l_rA);
  do_sm(NTILES - 1, sbB0, PlB0, scB0, m_rB, l_rB);
  vload();                                   // V(128)
  LGKM_BAR();
  do_pv(NTILES - 1, PlA0, scA0, oA); do_pv(NTILES - 1, PlB0, scB0, oB);

  // ---- finalize ----
  if ((ln & 15) == 0) { lA[srow] = l_rA; lB[srow] = l_rB; }
  LGKM_BAR();
  float ilA[2][4], ilB[2][4];
  #pragma unroll
  for (int mt = 0; mt < 2; ++mt)
    #pragma unroll
    for (int r = 0; r < 4; ++r) {
      ilA[mt][r] = 1.0f / lA[mt * 16 + g * 4 + r];
      ilB[mt][r] = 1.0f / lB[mt * 16 + g * 4 + r];
    }
  #pragma unroll
  for (int mt = 0; mt < 2; ++mt)
    #pragma unroll
    for (int dt = 0; dt < 8; ++dt)
      #pragma unroll
      for (int r = 0; r < 4; ++r) {
        const size_t rowA = (size_t)(b * SS + q0 + mt * 16 + g * 4 + r);
        out[rowA * HH + dbase + dt * 16 + li] = oA[mt][dt][r] * ilA[mt][r];
        out[(rowA + 32) * HH + dbase + dt * 16 + li] = oB[mt][dt][r] * ilB[mt][r];
      }
}

extern "C" void kernel_launch(void* const* d_in, const int* in_sizes, int n_in,
                              void* d_out, int out_size, void* d_ws, size_t ws_size,
                              hipStream_t stream) {
  const float* q        = (const float*)d_in[0];
  const float* key      = (const float*)d_in[1];
  const float* value    = (const float*)d_in[2];
  const float* prefix_k = (const float*)d_in[3];
  const float* prefix_v = (const float*)d_in[4];
  float* out = (float*)d_out;

  const size_t PLANE = (size_t)BB * CHUNKS_PB * 8;              // fp16 elems per plane
  const size_t NEED  = 2 * PLANE * sizeof(unsigned short);      // 67.6 MB

  if (ws_size >= NEED) {
    _Float16* kp = (_Float16*)d_ws;
    _Float16* vp = kp + PLANE;
    conv_k<<<dim3(CHUNKS_PB / 256, BB), 256, 0, stream>>>(prefix_k, key, kp);
    conv_v<<<dim3(CHUNKS_PB / 256, BB), 256, 0, stream>>>(prefix_v, value, vp);
    attn_fused<0><<<256, 512, 0, stream>>>(q, key, value, prefix_k, prefix_v, kp, vp, out);
  } else {
    attn_fused<1><<<256, 512, 0, stream>>>(q, key, value, prefix_k, prefix_v,
                                           nullptr, nullptr, out);
  }
}

// Round 10
// 590.291 us; speedup vs baseline: 4.8983x; 2.0041x over previous
//
#include <hip/hip_runtime.h>
#include <cstdint>
#include <cstddef>

// Problem constants
#define BB 4
#define SS 4096
#define HH 1024
#define PP 10
#define LL 4106              // P + S
#define NTILES 129
#define CHUNKS_PB (NTILES * 4096)   // 16B-chunks per batch plane (= 528384)
#define TILE_ELEMS (4096 * 8)       // fp16 elems per tile in a plane
#define LOG2E 1.44269504088896f

typedef __attribute__((ext_vector_type(8))) _Float16 half8v;  // 4 VGPR MFMA frag
typedef __attribute__((ext_vector_type(4))) float float4v;

union hu16 { _Float16 h; unsigned short u; };

__device__ __forceinline__ half8v cvt8h(float4v f0, float4v f1) {
  half8v h;
  h[0] = (_Float16)f0[0]; h[1] = (_Float16)f0[1];
  h[2] = (_Float16)f0[2]; h[3] = (_Float16)f0[3];
  h[4] = (_Float16)f1[0]; h[5] = (_Float16)f1[1];
  h[6] = (_Float16)f1[2]; h[7] = (_Float16)f1[3];
  return h;
}

// DPP row-16 reductions (VALU pipe); + shfl_xor(16) extends to 32-lane rows.
template<int C>
__device__ __forceinline__ float dppf(float x) {
  return __int_as_float(
      __builtin_amdgcn_update_dpp(0, __float_as_int(x), C, 0xF, 0xF, true));
}
__device__ __forceinline__ float row32_max(float x) {
  x = fmaxf(x, dppf<0xB1>(x));
  x = fmaxf(x, dppf<0x4E>(x));
  x = fmaxf(x, dppf<0x140>(x));
  x = fmaxf(x, dppf<0x141>(x));
  x = fmaxf(x, __shfl_xor(x, 16));
  return x;
}
__device__ __forceinline__ float row32_sum(float x) {
  x += dppf<0xB1>(x);
  x += dppf<0x4E>(x);
  x += dppf<0x140>(x);
  x += dppf<0x141>(x);
  x += __shfl_xor(x, 16);
  return x;
}

#define LGKM_BAR() do { \
  asm volatile("s_waitcnt lgkmcnt(0)" ::: "memory"); \
  __builtin_amdgcn_s_barrier(); \
  asm volatile("" ::: "memory"); } while (0)

// ---------- pre-kernels: fp16 planes in MFMA-fragment order (unchanged) ----------
__global__ __launch_bounds__(256) void conv_k(const float* __restrict__ prefix_k,
                                              const float* __restrict__ key,
                                              _Float16* __restrict__ kp) {
  const int b = blockIdx.y;
  const int id = blockIdx.x * 256 + threadIdx.x;       // < CHUNKS_PB
  const int li = id & 15, g = (id >> 4) & 3, ktp = (id >> 6) & 31,
            nt = (id >> 11) & 1, it = id >> 12;
  const int n = it * 32 + nt * 16 + li;
  const int d = ktp * 32 + g * 8;
  float4v f0 = {0.f, 0.f, 0.f, 0.f}, f1 = {0.f, 0.f, 0.f, 0.f};
  if (n < LL) {
    const float* src = (n < PP) ? prefix_k + (size_t)n * HH + d
                                : key + ((size_t)b * SS + (n - PP)) * HH + d;
    f0 = *(const float4v*)src; f1 = *(const float4v*)(src + 4);
  }
  *(half8v*)(kp + ((size_t)b * CHUNKS_PB + id) * 8) = cvt8h(f0, f1);
}

__global__ __launch_bounds__(256) void conv_v(const float* __restrict__ prefix_v,
                                              const float* __restrict__ value,
                                              _Float16* __restrict__ vp) {
  const int b = blockIdx.y;
  const int id = blockIdx.x * 256 + threadIdx.x;
  const int d = id & 1023, g = (id >> 10) & 3, it = id >> 12;
  const int nb = it * 32 + g * 8;
  half8v h;
  #pragma unroll
  for (int j = 0; j < 8; ++j) {
    int n = nb + j;
    float f = 0.f;
    if (n < LL)
      f = (n < PP) ? prefix_v[(size_t)n * HH + d]
                   : value[((size_t)b * SS + (n - PP)) * HH + d];
    h[j] = (_Float16)f;
  }
  *(half8v*)(vp + ((size_t)b * CHUNKS_PB + id) * 8) = h;
}

// ---------------- fused flash attention, v10: 16 waves, D-64/wave ----------------
// 512 blocks x 1024 threads. Wave w owns D-slice [64w, 64w+64), M=32 rows,
// KV tile 32. ~118 regs/wave -> 4 waves/SIMD (vs v7's 2): the L2 stream stalls
// of one wave are hidden under the MFMA/VALU of three others. Same v7 pipeline:
// 1 barrier/iter, 3-deep (QK(i) | softmax(i-1) | PV(i-2)), named LDS banks.
template<int PATH>
__global__ __launch_bounds__(1024, 4) void attn_fused(
    const float* __restrict__ q,
    const float* __restrict__ key,
    const float* __restrict__ value,
    const float* __restrict__ prefix_k,
    const float* __restrict__ prefix_v,
    const _Float16* __restrict__ kp,
    const _Float16* __restrict__ vp,
    float* __restrict__ out)
{
  __shared__ __align__(16) float sbuf0[16][32][33];       // 67.6 KB partials, bank 0
  __shared__ __align__(16) float sbuf1[16][32][33];       // bank 1
  __shared__ __align__(16) unsigned short Pl0[32][40];    // 2.56 KB each
  __shared__ __align__(16) unsigned short Pl1[32][40];
  __shared__ float sc0[32], sc1[32];
  __shared__ float l_l[32];

  const int tid = threadIdx.x;
  const int w = tid >> 6, ln = tid & 63, g = (ln >> 4) & 3, li = ln & 15;
  const int bid = blockIdx.x, xcd = bid & 7, b = xcd >> 1;
  const int qt = ((bid >> 3) << 1) | (xcd & 1);   // 0..127
  const int q0 = qt * 32;
  const int dbase = w * 64;

  // Q fragments fp16: A-layout row=li (+16 mt), k = kt*32 + g*8 + j
  half8v qf[2][2];
  #pragma unroll
  for (int mt = 0; mt < 2; ++mt)
    #pragma unroll
    for (int kt = 0; kt < 2; ++kt) {
      const float* p = q + ((size_t)(b * SS + q0 + mt * 16 + li)) * HH + dbase + kt * 32 + g * 8;
      qf[mt][kt] = cvt8h(*(const float4v*)p, *(const float4v*)(p + 4));
    }

  float4v z4 = {0.f, 0.f, 0.f, 0.f};
  float4v o[2][4];
  #pragma unroll
  for (int mt = 0; mt < 2; ++mt)
    #pragma unroll
    for (int dt = 0; dt < 4; ++dt) o[mt][dt] = z4;
  float m_r = -1e30f, l_r = 0.f;

  // K plane: chunk (((it*2+nt)*32 + (w*2+kt))*4 + g)*16 + li
  //   -> elem off = it*32768 + nt*16384 + (w*2+kt)*512 + (g*16+li)*8
  // V plane: chunk (it*4+g)*1024 + (dbase + dt*16 + li)
  //   -> elem off = it*32768 + g*8192 + (dbase+li)*8 + dt*128
  const _Float16* kbase = kp + (size_t)b * CHUNKS_PB * 8
                          + (size_t)(w * 2) * 512 + (g * 16 + li) * 8;
  const _Float16* vbase = vp + (size_t)b * CHUNKS_PB * 8
                          + (size_t)g * 8192 + (size_t)(dbase + li) * 8;

  half8v kreg[2][2];   // [nt][kt], K(i) during region i
  half8v vreg[4];      // [dt],     V(i-1) during region i (used by pv at i+1)
  if constexpr (PATH == 0) {
    #pragma unroll
    for (int nt = 0; nt < 2; ++nt)
      #pragma unroll
      for (int kt = 0; kt < 2; ++kt)
        kreg[nt][kt] = *(const half8v*)(kbase + nt * 16384 + kt * 512);
    kbase += TILE_ELEMS;
  }

  const int srow = tid >> 5;        // softmax: 1 element/thread
  const int scol = tid & 31;

  auto do_qk = [&](int i, float (*sb)[32][33]) __attribute__((always_inline)) {
    float4v sacc[2][2];
    sacc[0][0] = z4; sacc[0][1] = z4; sacc[1][0] = z4; sacc[1][1] = z4;
    #pragma unroll
    for (int kt = 0; kt < 2; ++kt) {
      half8v kb[2];
      if constexpr (PATH == 0) {
        kb[0] = kreg[0][kt]; kb[1] = kreg[1][kt];
      } else {
        #pragma unroll
        for (int nt = 0; nt < 2; ++nt) {
          int n = i * 32 + nt * 16 + li;
          int nc = (n < LL) ? n : 0;
          const float* kpp = (nc < PP) ? (prefix_k + (size_t)nc * HH)
                                       : (key + ((size_t)b * SS + (nc - PP)) * HH);
          kpp += dbase + kt * 32 + g * 8;
          kb[nt] = cvt8h(*(const float4v*)kpp, *(const float4v*)(kpp + 4));
        }
      }
      #pragma unroll
      for (int mt = 0; mt < 2; ++mt)
        #pragma unroll
        for (int nt = 0; nt < 2; ++nt)
          sacc[mt][nt] = __builtin_amdgcn_mfma_f32_16x16x32_f16(qf[mt][kt], kb[nt], sacc[mt][nt], 0, 0, 0);
    }
    // C/D: row = g*4+r, col = li
    #pragma unroll
    for (int mt = 0; mt < 2; ++mt)
      #pragma unroll
      for (int nt = 0; nt < 2; ++nt)
        #pragma unroll
        for (int r = 0; r < 4; ++r)
          sb[w][mt * 16 + g * 4 + r][nt * 16 + li] = sacc[mt][nt][r];
    // prefetch kreg <- K(i+1)  (benign 1-tile overrun into vp after last tile)
    if constexpr (PATH == 0) {
      #pragma unroll
      for (int nt = 0; nt < 2; ++nt)
        #pragma unroll
        for (int kt = 0; kt < 2; ++kt)
          kreg[nt][kt] = *(const half8v*)(kbase + nt * 16384 + kt * 512);
      kbase += TILE_ELEMS;
    }
  };

  auto do_sm = [&](int t, const float (*sb)[32][33],
                   unsigned short (*plw)[40], float* scw)
      __attribute__((always_inline)) {
    float s = 0.f;
    #pragma unroll
    for (int i = 0; i < 16; ++i) s += sb[i][srow][scol];
    if constexpr (PATH == 1) {
      if (t * 32 + scol >= LL) s = -1e30f;
    }
    const float mx = row32_max(s);
    const float m_new = fmaxf(m_r, mx);
    const float scp = exp2f((m_r - m_new) * LOG2E);
    const float p = exp2f((s - m_new) * LOG2E);
    const float ts = row32_sum(p);
    l_r = l_r * scp + ts;
    m_r = m_new;
    hu16 hp; hp.h = (_Float16)p;
    plw[srow][scol] = hp.u;
    if (scol == 0) scw[srow] = scp;
  };

  auto do_pv = [&](int t, const unsigned short (*plr)[40], const float* scr)
      __attribute__((always_inline)) {
    float scc[2][4];
    #pragma unroll
    for (int mt = 0; mt < 2; ++mt)
      #pragma unroll
      for (int r = 0; r < 4; ++r)
        scc[mt][r] = scr[mt * 16 + g * 4 + r];
    #pragma unroll
    for (int mt = 0; mt < 2; ++mt)
      #pragma unroll
      for (int dt = 0; dt < 4; ++dt)
        #pragma unroll
        for (int r = 0; r < 4; ++r)
          o[mt][dt][r] *= scc[mt][r];
    half8v pa0 = *(const half8v*)&plr[li][g * 8];
    half8v pa1 = *(const half8v*)&plr[16 + li][g * 8];
    #pragma unroll
    for (int dt = 0; dt < 4; ++dt) {
      half8v vb;
      if constexpr (PATH == 0) {
        vb = vreg[dt];
      } else {
        const int d = dbase + dt * 16 + li;
        #pragma unroll
        for (int j = 0; j < 8; ++j) {
          int n = t * 32 + g * 8 + j;
          int nc = (n < LL) ? n : 0;    // clamped rows have P==0
          float f = (nc < PP) ? prefix_v[(size_t)nc * HH + d]
                              : value[((size_t)b * SS + (nc - PP)) * HH + d];
          vb[j] = (_Float16)f;
        }
      }
      o[0][dt] = __builtin_amdgcn_mfma_f32_16x16x32_f16(pa0, vb, o[0][dt], 0, 0, 0);
      o[1][dt] = __builtin_amdgcn_mfma_f32_16x16x32_f16(pa1, vb, o[1][dt], 0, 0, 0);
    }
  };

  auto load_v = [&]() __attribute__((always_inline)) {
    if constexpr (PATH == 0) {
      #pragma unroll
      for (int dt = 0; dt < 4; ++dt)
        vreg[dt] = *(const half8v*)(vbase + dt * 128);
      vbase += TILE_ELEMS;
    }
  };

  // ---- pipeline: prologue / steady (x2 unrolled) / epilogue (v7 shape) ----
  do_qk(0, sbuf0);
  LGKM_BAR();
  do_qk(1, sbuf1); do_sm(0, sbuf0, Pl0, sc0); load_v();
  LGKM_BAR();
  int i = 2;
  for (; i + 1 < NTILES; i += 2) {
    do_qk(i, sbuf0);
    do_pv(i - 2, Pl0, sc0);
    do_sm(i - 1, sbuf1, Pl1, sc1);
    load_v();
    LGKM_BAR();
    do_qk(i + 1, sbuf1);
    do_pv(i - 1, Pl1, sc1);
    do_sm(i, sbuf0, Pl0, sc0);
    load_v();
    LGKM_BAR();
  }
  // NTILES odd: final even-bank steady iter (i == NTILES-1 == 128)
  do_qk(NTILES - 1, sbuf0);
  do_pv(NTILES - 3, Pl0, sc0);
  do_sm(NTILES - 2, sbuf1, Pl1, sc1);
  load_v();
  LGKM_BAR();
  // epilogue
  do_pv(NTILES - 2, Pl1, sc1);
  do_sm(NTILES - 1, sbuf0, Pl0, sc0);
  load_v();
  LGKM_BAR();
  do_pv(NTILES - 1, Pl0, sc0);

  // ---- finalize ----
  if (scol == 0) l_l[srow] = l_r;
  LGKM_BAR();
  float il[2][4];
  #pragma unroll
  for (int mt = 0; mt < 2; ++mt)
    #pragma unroll
    for (int r = 0; r < 4; ++r)
      il[mt][r] = 1.0f / l_l[mt * 16 + g * 4 + r];
  #pragma unroll
  for (int mt = 0; mt < 2; ++mt)
    #pragma unroll
    for (int dt = 0; dt < 4; ++dt)
      #pragma unroll
      for (int r = 0; r < 4; ++r)
        out[((size_t)(b * SS + q0 + mt * 16 + g * 4 + r)) * HH + dbase + dt * 16 + li]
            = o[mt][dt][r] * il[mt][r];
}

extern "C" void kernel_launch(void* const* d_in, const int* in_sizes, int n_in,
                              void* d_out, int out_size, void* d_ws, size_t ws_size,
                              hipStream_t stream) {
  const float* q        = (const float*)d_in[0];
  const float* key      = (const float*)d_in[1];
  const float* value    = (const float*)d_in[2];
  const float* prefix_k = (const float*)d_in[3];
  const float* prefix_v = (const float*)d_in[4];
  float* out = (float*)d_out;

  const size_t PLANE = (size_t)BB * CHUNKS_PB * 8;              // fp16 elems per plane
  const size_t NEED  = 2 * PLANE * sizeof(unsigned short);      // 67.6 MB

  if (ws_size >= NEED) {
    _Float16* kp = (_Float16*)d_ws;
    _Float16* vp = kp + PLANE;
    conv_k<<<dim3(CHUNKS_PB / 256, BB), 256, 0, stream>>>(prefix_k, key, kp);
    conv_v<<<dim3(CHUNKS_PB / 256, BB), 256, 0, stream>>>(prefix_v, value, vp);
    attn_fused<0><<<512, 1024, 0, stream>>>(q, key, value, prefix_k, prefix_v, kp, vp, out);
  } else {
    attn_fused<1><<<512, 1024, 0, stream>>>(q, key, value, prefix_k, prefix_v,
                                            nullptr, nullptr, out);
  }
}